// Round 11
// baseline (236.486 us; speedup 1.0000x reference)
//
#include <hip/hip_runtime.h>

// StackedGIN: L=3 layers of { agg = h + scatter_sum(h[src] -> dst);
//   h = relu( relu(agg@W1+B1) @ W2 + B2 ) }, then out = h@Wc + Bc.
// N=50000, E=800000, D=96, C=10.
//
// R1: float4 gather, unroll x4.  R2: wave-scan slot assignment.
// R3: MLP via bf16 MFMA.         R4: h/agg stored bf16 (gather halved).
// R5: prep fuse; classifier fused into layer-3 MLP epilogue.
// R6: plain-dispatch CSR build (coop grid.sync 5x slower on scatter phases).
// R7 FAILED (reverted): agg fused into MLP capped gather occupancy.
// R8: csr as u16; prep merged into hist.
// R9: custom zero_kernel (neutral; the 43us fillBuffer was harness reset
//     outside the timed region — misattribution, logged).
// R10->R11: raise memory-level parallelism in the three latency-bound
//     kernels: fill 4 atomic chains/thread (int4 loads), hist 4 atomics/
//     thread (int4), aggb gather unroll 4->8.
// ws layout: hbuf(N*96 bf16) | aggbuf(N*96 bf16) | start(N) | cursor(N) |
//            deg(N) | counter(1) | csr16(E u16) | wt(6*9216 u16)

#define TPB 256
#define LDA 104  // bf16 elems per LDS row: 96 + 8 pad

typedef __attribute__((ext_vector_type(8))) short bfrag8;
typedef __attribute__((ext_vector_type(8))) unsigned short u16x8;
typedef __attribute__((ext_vector_type(4))) float f32x4;

__device__ inline unsigned short f2bf(float x) {  // RNE f32 -> bf16 bits
  unsigned int u = __float_as_uint(x);
  unsigned int r = u + 0x7FFFu + ((u >> 16) & 1u);
  return (unsigned short)(r >> 16);
}
__device__ inline float bf2f(unsigned short u) {
  return __uint_as_float(((unsigned int)u) << 16);
}

__global__ __launch_bounds__(TPB) void zero_kernel(int* __restrict__ p, int n) {
  int i = blockIdx.x * TPB + threadIdx.x;
  if (i < n) p[i] = 0;
}

// threads [0,ceil(E/4)): histogram of dst, 4 edges/thread (4 independent
// atomic chains). Then weight transpose->bf16 and x->bf16 streaming jobs.
__global__ __launch_bounds__(TPB) void histprep_kernel(
    const int* __restrict__ dst, int* __restrict__ deg, int E,
    const float* __restrict__ W1, const float* __restrict__ W2,
    unsigned short* __restrict__ wt,
    const float4* __restrict__ x4, u16x8* __restrict__ h8, int total8) {
  int t = blockIdx.x * TPB + threadIdx.x;
  const int E4 = (E + 3) >> 2;
  if (t < E4) {
    int base = 4 * t;
    if (base + 4 <= E) {
      int4 d4 = *reinterpret_cast<const int4*>(dst + base);
      atomicAdd(&deg[d4.x], 1);
      atomicAdd(&deg[d4.y], 1);
      atomicAdd(&deg[d4.z], 1);
      atomicAdd(&deg[d4.w], 1);
    } else {
      for (int e = base; e < E; e++) atomicAdd(&deg[dst[e]], 1);
    }
    return;
  }
  t -= E4;
  const int wjobs = 6 * 9216;
  if (t < wjobs) {
    int mat = t / 9216, idx = t - mat * 9216;
    int l = mat >> 1, which = mat & 1;
    int k = idx / 96, n = idx - k * 96;
    const float* src = (which ? W2 : W1) + (size_t)l * 9216;
    wt[(size_t)mat * 9216 + n * 96 + k] = f2bf(src[k * 96 + n]);
  } else {
    int u = t - wjobs;
    if (u < total8) {
      float4 a = x4[2 * u], b = x4[2 * u + 1];
      u16x8 o;
      o[0] = f2bf(a.x); o[1] = f2bf(a.y); o[2] = f2bf(a.z); o[3] = f2bf(a.w);
      o[4] = f2bf(b.x); o[5] = f2bf(b.y); o[6] = f2bf(b.z); o[7] = f2bf(b.w);
      h8[u] = o;
    }
  }
}

// start[i] = running sum of deg in wave-chunked order (order irrelevant).
__global__ __launch_bounds__(TPB) void assign_kernel(const int* __restrict__ deg,
                                                     int* __restrict__ start,
                                                     int* __restrict__ cursor,
                                                     int* __restrict__ counter, int n) {
  int i = blockIdx.x * TPB + threadIdx.x;
  int d = (i < n) ? deg[i] : 0;
  int lane = threadIdx.x & 63;
  int incl = d;
#pragma unroll
  for (int off = 1; off < 64; off <<= 1) {
    int v = __shfl_up(incl, off, 64);
    if (lane >= off) incl += v;
  }
  int waveTotal = __shfl(incl, 63, 64);
  int base = 0;
  if (lane == 63) base = atomicAdd(counter, waveTotal);
  base = __shfl(base, 63, 64);
  int st = base + incl - d;
  if (i < n) { start[i] = st; cursor[i] = st; }
}

// fill: 4 edges per thread (int4 loads, 4 independent atomic->store chains);
// csr entries are u16 (src < 65536).
__global__ __launch_bounds__(TPB) void fill_kernel(const int* __restrict__ src,
                                                   const int* __restrict__ dst,
                                                   int* __restrict__ cursor,
                                                   unsigned short* __restrict__ csr16,
                                                   int E) {
  int t = blockIdx.x * TPB + threadIdx.x;
  int base = 4 * t;
  if (base + 4 <= E) {
    int4 d4 = *reinterpret_cast<const int4*>(dst + base);
    int4 s4 = *reinterpret_cast<const int4*>(src + base);
    int slot0 = atomicAdd(&cursor[d4.x], 1);
    int slot1 = atomicAdd(&cursor[d4.y], 1);
    int slot2 = atomicAdd(&cursor[d4.z], 1);
    int slot3 = atomicAdd(&cursor[d4.w], 1);
    csr16[slot0] = (unsigned short)s4.x;
    csr16[slot1] = (unsigned short)s4.y;
    csr16[slot2] = (unsigned short)s4.z;
    csr16[slot3] = (unsigned short)s4.w;
  } else {
    for (int e = base; e < E; e++) {
      int slot = atomicAdd(&cursor[dst[e]], 1);
      csr16[slot] = (unsigned short)src[e];
    }
  }
}

// agg[i][c8] = h[i][c8] + sum_{j in row i} h[csr[j]][c8]; bf16 in/out,
// f32 accumulate. 12 threads/node (96/8), unroll x8 for MLP.
__global__ __launch_bounds__(TPB) void aggb_kernel(const u16x8* __restrict__ hin8,
                                                   u16x8* __restrict__ hout8,
                                                   const int* __restrict__ start,
                                                   const int* __restrict__ deg,
                                                   const unsigned short* __restrict__ csr16,
                                                   int n) {
  int t = blockIdx.x * TPB + threadIdx.x;
  if (t >= n * 12) return;
  int i = t / 12;
  int f = t - i * 12;
  u16x8 self = hin8[t];
  float acc[8];
#pragma unroll
  for (int k = 0; k < 8; k++) acc[k] = bf2f(self[k]);
  int s = start[i], e = s + deg[i];
  int j = s;
  for (; j + 8 <= e; j += 8) {
    int i0 = csr16[j],     i1 = csr16[j + 1], i2 = csr16[j + 2], i3 = csr16[j + 3];
    int i4 = csr16[j + 4], i5 = csr16[j + 5], i6 = csr16[j + 6], i7 = csr16[j + 7];
    u16x8 v0 = hin8[(size_t)i0 * 12 + f];
    u16x8 v1 = hin8[(size_t)i1 * 12 + f];
    u16x8 v2 = hin8[(size_t)i2 * 12 + f];
    u16x8 v3 = hin8[(size_t)i3 * 12 + f];
    u16x8 v4 = hin8[(size_t)i4 * 12 + f];
    u16x8 v5 = hin8[(size_t)i5 * 12 + f];
    u16x8 v6 = hin8[(size_t)i6 * 12 + f];
    u16x8 v7 = hin8[(size_t)i7 * 12 + f];
#pragma unroll
    for (int k = 0; k < 8; k++)
      acc[k] += ((bf2f(v0[k]) + bf2f(v1[k])) + (bf2f(v2[k]) + bf2f(v3[k]))) +
                ((bf2f(v4[k]) + bf2f(v5[k])) + (bf2f(v6[k]) + bf2f(v7[k])));
  }
  if (j + 4 <= e) {
    int i0 = csr16[j], i1 = csr16[j + 1], i2 = csr16[j + 2], i3 = csr16[j + 3];
    u16x8 v0 = hin8[(size_t)i0 * 12 + f];
    u16x8 v1 = hin8[(size_t)i1 * 12 + f];
    u16x8 v2 = hin8[(size_t)i2 * 12 + f];
    u16x8 v3 = hin8[(size_t)i3 * 12 + f];
#pragma unroll
    for (int k = 0; k < 8; k++)
      acc[k] += (bf2f(v0[k]) + bf2f(v1[k])) + (bf2f(v2[k]) + bf2f(v3[k]));
    j += 4;
  }
  for (; j < e; j++) {
    u16x8 v = hin8[(size_t)csr16[j] * 12 + f];
#pragma unroll
    for (int k = 0; k < 8; k++) acc[k] += bf2f(v[k]);
  }
  u16x8 o;
#pragma unroll
  for (int k = 0; k < 8; k++) o[k] = f2bf(acc[k]);
  hout8[t] = o;
}

// h = relu( relu(agg@W1+B1) @ W2 + B2 ); LAST also computes out = h@Wc + Bc
// (h never stored for the last layer). Block: 64 rows, 4 waves x 16-row stripe.
template <bool LAST>
__global__ __launch_bounds__(TPB) void mlp_mfma_kernel(
    const u16x8* __restrict__ in8, const unsigned short* __restrict__ wt1,
    const unsigned short* __restrict__ wt2, const float* __restrict__ B1,
    const float* __restrict__ B2, unsigned short* __restrict__ out,
    const float* __restrict__ Wc, const float* __restrict__ Bc,
    float* __restrict__ outf, int nrows) {
  __shared__ unsigned short A_lds[64 * LDA];   // A tile, later Z tile
  __shared__ unsigned short W1_lds[96 * LDA];
  __shared__ unsigned short W2_lds[96 * LDA];
  const int tid = threadIdx.x;
  const int row0 = blockIdx.x * 64;

  // stage A (already bf16), rows [row0, row0+64)
  for (int t = tid; t < 64 * 12; t += TPB) {
    int r = t / 12, c8 = t - r * 12;
    int gr = row0 + r;
    u16x8 v = {};
    if (gr < nrows) v = in8[(size_t)gr * 12 + c8];
    *reinterpret_cast<u16x8*>(&A_lds[r * LDA + 8 * c8]) = v;
  }
  // stage Wt1, Wt2 (bf16, 16B chunks)
  for (int t = tid; t < 2 * 1152; t += TPB) {
    int which = t / 1152, idx = t - which * 1152;
    int n = idx / 12, c8 = idx - n * 12;
    const unsigned short* src = (which ? wt2 : wt1) + n * 96 + 8 * c8;
    bfrag8 v = *reinterpret_cast<const bfrag8*>(src);
    unsigned short* dp = (which ? W2_lds : W1_lds) + n * LDA + 8 * c8;
    *reinterpret_cast<bfrag8*>(dp) = v;
  }
  __syncthreads();

  const int lane = tid & 63;
  const int w = tid >> 6;     // wave id: rows [16w, 16w+16)
  const int nl = lane & 15;   // frag row (A) / col (B,D)
  const int q = lane >> 4;    // k-quarter
  const int arow = 16 * w + nl;

  bfrag8 afrag[3];
#pragma unroll
  for (int s = 0; s < 3; s++)
    afrag[s] = *reinterpret_cast<const bfrag8*>(&A_lds[arow * LDA + 32 * s + 8 * q]);

  // GEMM1 -> relu -> Z (bf16) into this wave's own A stripe (no barrier needed)
#pragma unroll
  for (int cb = 0; cb < 6; cb++) {
    f32x4 acc = {0.f, 0.f, 0.f, 0.f};
#pragma unroll
    for (int s = 0; s < 3; s++) {
      bfrag8 bfr = *reinterpret_cast<const bfrag8*>(
          &W1_lds[(16 * cb + nl) * LDA + 32 * s + 8 * q]);
      acc = __builtin_amdgcn_mfma_f32_16x16x32_bf16(afrag[s], bfr, acc, 0, 0, 0);
    }
    float b = B1[16 * cb + nl];
#pragma unroll
    for (int i = 0; i < 4; i++) {
      int m = 16 * w + 4 * q + i;
      A_lds[m * LDA + 16 * cb + nl] = f2bf(fmaxf(acc[i] + b, 0.f));
    }
  }

  bfrag8 zfrag[3];
#pragma unroll
  for (int s = 0; s < 3; s++)
    zfrag[s] = *reinterpret_cast<const bfrag8*>(&A_lds[arow * LDA + 32 * s + 8 * q]);

  float oacc[40];  // LAST only: per-lane partial out[i][c], static-indexed
#pragma unroll
  for (int t2 = 0; t2 < 40; t2++) oacc[t2] = 0.f;

#pragma unroll
  for (int cb = 0; cb < 6; cb++) {
    f32x4 acc = {0.f, 0.f, 0.f, 0.f};
#pragma unroll
    for (int s = 0; s < 3; s++) {
      bfrag8 bfr = *reinterpret_cast<const bfrag8*>(
          &W2_lds[(16 * cb + nl) * LDA + 32 * s + 8 * q]);
      acc = __builtin_amdgcn_mfma_f32_16x16x32_bf16(zfrag[s], bfr, acc, 0, 0, 0);
    }
    float b = B2[16 * cb + nl];
#pragma unroll
    for (int i = 0; i < 4; i++) {
      float hv = fmaxf(acc[i] + b, 0.f);
      if (!LAST) {
        int m = 16 * w + 4 * q + i;
        int gr = row0 + m;
        if (gr < nrows) out[(size_t)gr * 96 + 16 * cb + nl] = f2bf(hv);
      } else {
#pragma unroll
        for (int c = 0; c < 10; c++)
          oacc[i * 10 + c] += hv * Wc[(16 * cb + nl) * 10 + c];
      }
    }
  }

  if (LAST) {
    // reduce over the 16 nl-lanes within each q-group
#pragma unroll
    for (int m = 1; m < 16; m <<= 1) {
#pragma unroll
      for (int t2 = 0; t2 < 40; t2++) oacc[t2] += __shfl_xor(oacc[t2], m, 64);
    }
#pragma unroll
    for (int i = 0; i < 4; i++) {
      int gr = row0 + 16 * w + 4 * q + i;
      if (gr < nrows && nl < 10) {
        float v = 0.f;
#pragma unroll
        for (int c = 0; c < 10; c++)
          if (nl == c) v = oacc[i * 10 + c];
        outf[(size_t)gr * 10 + nl] = v + Bc[nl];
      }
    }
  }
}

extern "C" void kernel_launch(void* const* d_in, const int* in_sizes, int n_in,
                              void* d_out, int out_size, void* d_ws, size_t ws_size,
                              hipStream_t stream) {
  const float* x  = (const float*)d_in[0];
  const int*   ei = (const int*)d_in[1];
  const float* W1 = (const float*)d_in[2];
  const float* B1 = (const float*)d_in[3];
  const float* W2 = (const float*)d_in[4];
  const float* B2 = (const float*)d_in[5];
  const float* Wc = (const float*)d_in[6];
  const float* Bc = (const float*)d_in[7];
  float* out = (float*)d_out;

  const int N = in_sizes[0] / 96;
  const int E = in_sizes[1] / 2;
  const int* src = ei;       // edge_index[0]
  const int* dst = ei + E;   // edge_index[1]

  unsigned short* hbuf   = (unsigned short*)d_ws;        // N*96 bf16
  unsigned short* aggbuf = hbuf + (size_t)N * 96;        // N*96 bf16
  int* start   = (int*)(aggbuf + (size_t)N * 96);
  int* cursor  = start + N;
  int* deg     = cursor + N;
  int* counter = deg + N;
  unsigned short* csr16 = (unsigned short*)(counter + 1);  // E u16
  unsigned short* wt    = csr16 + (size_t)E;               // 6*9216 u16

  zero_kernel<<<(N + 1 + TPB - 1) / TPB, TPB, 0, stream>>>(deg, N + 1);

  const int total8 = N * 12;
  const int E4 = (E + 3) / 4;
  const int histprep_jobs = E4 + 6 * 9216 + total8;
  histprep_kernel<<<(histprep_jobs + TPB - 1) / TPB, TPB, 0, stream>>>(
      dst, deg, E, W1, W2, wt, (const float4*)x, (u16x8*)hbuf, total8);

  assign_kernel<<<(N + TPB - 1) / TPB, TPB, 0, stream>>>(deg, start, cursor, counter, N);
  fill_kernel<<<(E4 + TPB - 1) / TPB, TPB, 0, stream>>>(src, dst, cursor, csr16, E);

  for (int l = 0; l < 3; l++) {
    aggb_kernel<<<((N * 12) + TPB - 1) / TPB, TPB, 0, stream>>>(
        (const u16x8*)hbuf, (u16x8*)aggbuf, start, deg, csr16, N);
    const unsigned short* wt1 = wt + (size_t)(l * 2) * 9216;
    const unsigned short* wt2 = wt + (size_t)(l * 2 + 1) * 9216;
    const float* b1 = B1 + (size_t)l * 96;
    const float* b2 = B2 + (size_t)l * 96;
    if (l < 2)
      mlp_mfma_kernel<false><<<(N + 63) / 64, TPB, 0, stream>>>(
          (const u16x8*)aggbuf, wt1, wt2, b1, b2, hbuf, Wc, Bc, out, N);
    else
      mlp_mfma_kernel<true><<<(N + 63) / 64, TPB, 0, stream>>>(
          (const u16x8*)aggbuf, wt1, wt2, b1, b2, hbuf, Wc, Bc, out, N);
  }
}

// Round 12
// 189.152 us; speedup vs baseline: 1.2502x; 1.2502x over previous
//
#include <hip/hip_runtime.h>

// StackedGIN: L=3 layers of { agg = h + scatter_sum(h[src] -> dst);
//   h = relu( relu(agg@W1+B1) @ W2 + B2 ) }, then out = h@Wc + Bc.
// N=50000, E=800000, D=96, C=10.
//
// R1: float4 gather.  R2: wave-scan slots.  R3: bf16 MFMA MLP.
// R4: h/agg bf16.  R5: prep fuse + fused classifier.  R6: no coop launch.
// R7 FAILED: agg-in-MLP capped occupancy.  R8: u16 csr.  R9: own zero.
// R10 NEUTRAL: more atomic chains didn't help -> fill is line-ping-pong
//     bound (40MB write-back for a 1.6MB buffer = cross-XCD migration).
// R11: bucketed CSR (stride 64, no hist/assign; deg=cursor, start=i*64)
//      + XCD-partitioned fill: group g=blockIdx&7 owns dst range g ->
//      cursor/csr lines stay in one XCD's L2. aggb loads 8 indices per
//      u16x8 (bucket rows 16B-aligned).
// ws layout: hbuf(N*96 bf16) | aggbuf(N*96 bf16) | cursor(N) |
//            csr16(N*64 u16) | wt(6*9216 u16)

#define TPB 256
#define LDA 104  // bf16 elems per LDS row: 96 + 8 pad
#define BS 64    // csr bucket stride per node

typedef __attribute__((ext_vector_type(8))) short bfrag8;
typedef __attribute__((ext_vector_type(8))) unsigned short u16x8;
typedef __attribute__((ext_vector_type(4))) float f32x4;

__device__ inline unsigned short f2bf(float x) {  // RNE f32 -> bf16 bits
  unsigned int u = __float_as_uint(x);
  unsigned int r = u + 0x7FFFu + ((u >> 16) & 1u);
  return (unsigned short)(r >> 16);
}
__device__ inline float bf2f(unsigned short u) {
  return __uint_as_float(((unsigned int)u) << 16);
}

// jobs: [0,N) zero cursor; then weight transpose->bf16; then x->bf16.
__global__ __launch_bounds__(TPB) void prep_kernel(
    int* __restrict__ cursor, int N,
    const float* __restrict__ W1, const float* __restrict__ W2,
    unsigned short* __restrict__ wt,
    const float4* __restrict__ x4, u16x8* __restrict__ h8, int total8) {
  int t = blockIdx.x * TPB + threadIdx.x;
  if (t < N) { cursor[t] = 0; return; }
  t -= N;
  const int wjobs = 6 * 9216;
  if (t < wjobs) {
    int mat = t / 9216, idx = t - mat * 9216;
    int l = mat >> 1, which = mat & 1;
    int k = idx / 96, n = idx - k * 96;
    const float* src = (which ? W2 : W1) + (size_t)l * 9216;
    wt[(size_t)mat * 9216 + n * 96 + k] = f2bf(src[k * 96 + n]);
  } else {
    int u = t - wjobs;
    if (u < total8) {
      float4 a = x4[2 * u], b = x4[2 * u + 1];
      u16x8 o;
      o[0] = f2bf(a.x); o[1] = f2bf(a.y); o[2] = f2bf(a.z); o[3] = f2bf(a.w);
      o[4] = f2bf(b.x); o[5] = f2bf(b.y); o[6] = f2bf(b.z); o[7] = f2bf(b.w);
      h8[u] = o;
    }
  }
}

// XCD-partitioned bucketed fill: group g = blockIdx&7 (round-robin XCD
// dispatch heuristic; correctness independent of mapping) owns dst range
// [g*chunk,(g+1)*chunk). Every group streams all edges (L3-served), handles
// only its own -> cursor/csr lines are single-XCD, no line migration.
__global__ __launch_bounds__(TPB) void fill_kernel(const int* __restrict__ src,
                                                   const int* __restrict__ dst,
                                                   int* __restrict__ cursor,
                                                   unsigned short* __restrict__ csr16,
                                                   int N, int E) {
  const int g = blockIdx.x & 7;
  const int bid = blockIdx.x >> 3;
  const int nblk = gridDim.x >> 3;
  const int chunk = (N + 7) >> 3;
  const int lo = g * chunk;
  const unsigned span = (unsigned)((N - lo < chunk) ? (N - lo) : chunk);
  const int gsz = nblk * TPB;
  for (int t = bid * TPB + threadIdx.x; 4 * t < E; t += gsz) {
    int base = 4 * t;
    if (base + 4 <= E) {
      int4 d4 = *reinterpret_cast<const int4*>(dst + base);
      int4 s4 = *reinterpret_cast<const int4*>(src + base);
      if ((unsigned)(d4.x - lo) < span) {
        int slot = atomicAdd(&cursor[d4.x], 1);
        csr16[(size_t)d4.x * BS + slot] = (unsigned short)s4.x;
      }
      if ((unsigned)(d4.y - lo) < span) {
        int slot = atomicAdd(&cursor[d4.y], 1);
        csr16[(size_t)d4.y * BS + slot] = (unsigned short)s4.y;
      }
      if ((unsigned)(d4.z - lo) < span) {
        int slot = atomicAdd(&cursor[d4.z], 1);
        csr16[(size_t)d4.z * BS + slot] = (unsigned short)s4.z;
      }
      if ((unsigned)(d4.w - lo) < span) {
        int slot = atomicAdd(&cursor[d4.w], 1);
        csr16[(size_t)d4.w * BS + slot] = (unsigned short)s4.w;
      }
    } else {
      for (int e = base; e < E; e++) {
        int d = dst[e];
        if ((unsigned)(d - lo) < span) {
          int slot = atomicAdd(&cursor[d], 1);
          csr16[(size_t)d * BS + slot] = (unsigned short)src[e];
        }
      }
    }
  }
}

// agg[i][c8] = h[i][c8] + sum_{j<deg[i]} h[csr[i*BS+j]][c8]; bf16 in/out,
// f32 accumulate. 12 threads/node; 8 neighbor indices loaded per u16x8.
__global__ __launch_bounds__(TPB) void aggb_kernel(const u16x8* __restrict__ hin8,
                                                   u16x8* __restrict__ hout8,
                                                   const int* __restrict__ deg,
                                                   const unsigned short* __restrict__ csr16,
                                                   int n) {
  int t = blockIdx.x * TPB + threadIdx.x;
  if (t >= n * 12) return;
  int i = t / 12;
  int f = t - i * 12;
  const unsigned short* row = csr16 + (size_t)i * BS;
  u16x8 self = hin8[t];
  float acc[8];
#pragma unroll
  for (int k = 0; k < 8; k++) acc[k] = bf2f(self[k]);
  int e = deg[i];
  int j = 0;
  for (; j + 8 <= e; j += 8) {
    u16x8 idx = *reinterpret_cast<const u16x8*>(row + j);
    u16x8 v0 = hin8[(size_t)idx[0] * 12 + f];
    u16x8 v1 = hin8[(size_t)idx[1] * 12 + f];
    u16x8 v2 = hin8[(size_t)idx[2] * 12 + f];
    u16x8 v3 = hin8[(size_t)idx[3] * 12 + f];
    u16x8 v4 = hin8[(size_t)idx[4] * 12 + f];
    u16x8 v5 = hin8[(size_t)idx[5] * 12 + f];
    u16x8 v6 = hin8[(size_t)idx[6] * 12 + f];
    u16x8 v7 = hin8[(size_t)idx[7] * 12 + f];
#pragma unroll
    for (int k = 0; k < 8; k++)
      acc[k] += ((bf2f(v0[k]) + bf2f(v1[k])) + (bf2f(v2[k]) + bf2f(v3[k]))) +
                ((bf2f(v4[k]) + bf2f(v5[k])) + (bf2f(v6[k]) + bf2f(v7[k])));
  }
  if (j + 4 <= e) {
    int i0 = row[j], i1 = row[j + 1], i2 = row[j + 2], i3 = row[j + 3];
    u16x8 v0 = hin8[(size_t)i0 * 12 + f];
    u16x8 v1 = hin8[(size_t)i1 * 12 + f];
    u16x8 v2 = hin8[(size_t)i2 * 12 + f];
    u16x8 v3 = hin8[(size_t)i3 * 12 + f];
#pragma unroll
    for (int k = 0; k < 8; k++)
      acc[k] += (bf2f(v0[k]) + bf2f(v1[k])) + (bf2f(v2[k]) + bf2f(v3[k]));
    j += 4;
  }
  for (; j < e; j++) {
    u16x8 v = hin8[(size_t)row[j] * 12 + f];
#pragma unroll
    for (int k = 0; k < 8; k++) acc[k] += bf2f(v[k]);
  }
  u16x8 o;
#pragma unroll
  for (int k = 0; k < 8; k++) o[k] = f2bf(acc[k]);
  hout8[t] = o;
}

// h = relu( relu(agg@W1+B1) @ W2 + B2 ); LAST also computes out = h@Wc + Bc
// (h never stored for the last layer). Block: 64 rows, 4 waves x 16-row stripe.
template <bool LAST>
__global__ __launch_bounds__(TPB) void mlp_mfma_kernel(
    const u16x8* __restrict__ in8, const unsigned short* __restrict__ wt1,
    const unsigned short* __restrict__ wt2, const float* __restrict__ B1,
    const float* __restrict__ B2, unsigned short* __restrict__ out,
    const float* __restrict__ Wc, const float* __restrict__ Bc,
    float* __restrict__ outf, int nrows) {
  __shared__ unsigned short A_lds[64 * LDA];   // A tile, later Z tile
  __shared__ unsigned short W1_lds[96 * LDA];
  __shared__ unsigned short W2_lds[96 * LDA];
  const int tid = threadIdx.x;
  const int row0 = blockIdx.x * 64;

  // stage A (already bf16), rows [row0, row0+64)
  for (int t = tid; t < 64 * 12; t += TPB) {
    int r = t / 12, c8 = t - r * 12;
    int gr = row0 + r;
    u16x8 v = {};
    if (gr < nrows) v = in8[(size_t)gr * 12 + c8];
    *reinterpret_cast<u16x8*>(&A_lds[r * LDA + 8 * c8]) = v;
  }
  // stage Wt1, Wt2 (bf16, 16B chunks)
  for (int t = tid; t < 2 * 1152; t += TPB) {
    int which = t / 1152, idx = t - which * 1152;
    int n = idx / 12, c8 = idx - n * 12;
    const unsigned short* src = (which ? wt2 : wt1) + n * 96 + 8 * c8;
    bfrag8 v = *reinterpret_cast<const bfrag8*>(src);
    unsigned short* dp = (which ? W2_lds : W1_lds) + n * LDA + 8 * c8;
    *reinterpret_cast<bfrag8*>(dp) = v;
  }
  __syncthreads();

  const int lane = tid & 63;
  const int w = tid >> 6;     // wave id: rows [16w, 16w+16)
  const int nl = lane & 15;   // frag row (A) / col (B,D)
  const int q = lane >> 4;    // k-quarter
  const int arow = 16 * w + nl;

  bfrag8 afrag[3];
#pragma unroll
  for (int s = 0; s < 3; s++)
    afrag[s] = *reinterpret_cast<const bfrag8*>(&A_lds[arow * LDA + 32 * s + 8 * q]);

  // GEMM1 -> relu -> Z (bf16) into this wave's own A stripe (no barrier needed)
#pragma unroll
  for (int cb = 0; cb < 6; cb++) {
    f32x4 acc = {0.f, 0.f, 0.f, 0.f};
#pragma unroll
    for (int s = 0; s < 3; s++) {
      bfrag8 bfr = *reinterpret_cast<const bfrag8*>(
          &W1_lds[(16 * cb + nl) * LDA + 32 * s + 8 * q]);
      acc = __builtin_amdgcn_mfma_f32_16x16x32_bf16(afrag[s], bfr, acc, 0, 0, 0);
    }
    float b = B1[16 * cb + nl];
#pragma unroll
    for (int i = 0; i < 4; i++) {
      int m = 16 * w + 4 * q + i;
      A_lds[m * LDA + 16 * cb + nl] = f2bf(fmaxf(acc[i] + b, 0.f));
    }
  }

  bfrag8 zfrag[3];
#pragma unroll
  for (int s = 0; s < 3; s++)
    zfrag[s] = *reinterpret_cast<const bfrag8*>(&A_lds[arow * LDA + 32 * s + 8 * q]);

  float oacc[40];  // LAST only: per-lane partial out[i][c], static-indexed
#pragma unroll
  for (int t2 = 0; t2 < 40; t2++) oacc[t2] = 0.f;

#pragma unroll
  for (int cb = 0; cb < 6; cb++) {
    f32x4 acc = {0.f, 0.f, 0.f, 0.f};
#pragma unroll
    for (int s = 0; s < 3; s++) {
      bfrag8 bfr = *reinterpret_cast<const bfrag8*>(
          &W2_lds[(16 * cb + nl) * LDA + 32 * s + 8 * q]);
      acc = __builtin_amdgcn_mfma_f32_16x16x32_bf16(zfrag[s], bfr, acc, 0, 0, 0);
    }
    float b = B2[16 * cb + nl];
#pragma unroll
    for (int i = 0; i < 4; i++) {
      float hv = fmaxf(acc[i] + b, 0.f);
      if (!LAST) {
        int m = 16 * w + 4 * q + i;
        int gr = row0 + m;
        if (gr < nrows) out[(size_t)gr * 96 + 16 * cb + nl] = f2bf(hv);
      } else {
#pragma unroll
        for (int c = 0; c < 10; c++)
          oacc[i * 10 + c] += hv * Wc[(16 * cb + nl) * 10 + c];
      }
    }
  }

  if (LAST) {
    // reduce over the 16 nl-lanes within each q-group
#pragma unroll
    for (int m = 1; m < 16; m <<= 1) {
#pragma unroll
      for (int t2 = 0; t2 < 40; t2++) oacc[t2] += __shfl_xor(oacc[t2], m, 64);
    }
#pragma unroll
    for (int i = 0; i < 4; i++) {
      int gr = row0 + 16 * w + 4 * q + i;
      if (gr < nrows && nl < 10) {
        float v = 0.f;
#pragma unroll
        for (int c = 0; c < 10; c++)
          if (nl == c) v = oacc[i * 10 + c];
        outf[(size_t)gr * 10 + nl] = v + Bc[nl];
      }
    }
  }
}

extern "C" void kernel_launch(void* const* d_in, const int* in_sizes, int n_in,
                              void* d_out, int out_size, void* d_ws, size_t ws_size,
                              hipStream_t stream) {
  const float* x  = (const float*)d_in[0];
  const int*   ei = (const int*)d_in[1];
  const float* W1 = (const float*)d_in[2];
  const float* B1 = (const float*)d_in[3];
  const float* W2 = (const float*)d_in[4];
  const float* B2 = (const float*)d_in[5];
  const float* Wc = (const float*)d_in[6];
  const float* Bc = (const float*)d_in[7];
  float* out = (float*)d_out;

  const int N = in_sizes[0] / 96;
  const int E = in_sizes[1] / 2;
  const int* src = ei;       // edge_index[0]
  const int* dst = ei + E;   // edge_index[1]

  unsigned short* hbuf   = (unsigned short*)d_ws;        // N*96 bf16
  unsigned short* aggbuf = hbuf + (size_t)N * 96;        // N*96 bf16
  int* cursor = (int*)(aggbuf + (size_t)N * 96);         // N int (deg after fill)
  unsigned short* csr16 = (unsigned short*)(cursor + N); // N*BS u16
  unsigned short* wt    = csr16 + (size_t)N * BS;        // 6*9216 u16

  const int total8 = N * 12;
  const int prep_jobs = N + 6 * 9216 + total8;
  prep_kernel<<<(prep_jobs + TPB - 1) / TPB, TPB, 0, stream>>>(
      cursor, N, W1, W2, wt, (const float4*)x, (u16x8*)hbuf, total8);

  fill_kernel<<<1024, TPB, 0, stream>>>(src, dst, cursor, csr16, N, E);

  for (int l = 0; l < 3; l++) {
    aggb_kernel<<<((N * 12) + TPB - 1) / TPB, TPB, 0, stream>>>(
        (const u16x8*)hbuf, (u16x8*)aggbuf, cursor, csr16, N);
    const unsigned short* wt1 = wt + (size_t)(l * 2) * 9216;
    const unsigned short* wt2 = wt + (size_t)(l * 2 + 1) * 9216;
    const float* b1 = B1 + (size_t)l * 96;
    const float* b2 = B2 + (size_t)l * 96;
    if (l < 2)
      mlp_mfma_kernel<false><<<(N + 63) / 64, TPB, 0, stream>>>(
          (const u16x8*)aggbuf, wt1, wt2, b1, b2, hbuf, Wc, Bc, out, N);
    else
      mlp_mfma_kernel<true><<<(N + 63) / 64, TPB, 0, stream>>>(
          (const u16x8*)aggbuf, wt1, wt2, b1, b2, hbuf, Wc, Bc, out, N);
  }
}